// Round 2
// baseline (976.533 us; speedup 1.0000x reference)
//
#include <hip/hip_runtime.h>

// CombinedLoss: 0.7*MSE + 0.3*mean_b softDTW_gamma.  B=64, T=1024, C=8, fp32.
// One block (1024 thr = 16 waves) per batch. Register-resident anti-diagonal DP:
// wave w owns rows [64w, 64w+63]; r_km1/r_km2 in VGPRs; neighbor row via
// DPP wave_shr:1; target column flows through lanes via DPP; lane0 reads fresh
// columns + halo from LDS, lane63 publishes halo. Waves skewed by D=16
// diagonals -> one barrier per 16 diagonals (143 total vs 2047).

constexpr int BB = 64;
constexpr int TT = 1024;
constexpr int CC = 8;
constexpr float ALPHA_ = 0.7f;
constexpr float GAMMA_ = 0.2f;
constexpr float FINF = 1000000000.0f;
constexpr int DB = 16;              // diagonals per barrier
constexpr int NSTEP = 143;          // ceil(2047/DB) + 15 skew steps

// lane l gets v from lane l-1; lane 0 gets old0.  (v_mov_b32 dpp wave_shr:1)
__device__ __forceinline__ float shflup1(float old0, float v) {
    return __int_as_float(__builtin_amdgcn_update_dpp(
        __float_as_int(old0), __float_as_int(v),
        0x138 /* wave_shr:1 */, 0xf, 0xf, false));
}

__global__ __launch_bounds__(1024) void sdtw_kernel(
    const float* __restrict__ pred, const float* __restrict__ target,
    float* __restrict__ ws)
{
    __shared__ float4 s_t4[TT][2];     // target columns (for lane-0 fresh reads)
    __shared__ float  s_y2[TT];
    __shared__ float  s_halo[16][64];  // ring of top-row r values per wave
    __shared__ float  s_red[16];

    const int b = blockIdx.x;
    const int i = threadIdx.x;         // row index
    const int w = i >> 6;
    const int l = i & 63;
    const int base = w << 6;

    const float* pr = pred   + ((size_t)b * TT + i) * CC;
    const float* tr = target + ((size_t)b * TT + i) * CC;
    float4 pa = ((const float4*)pr)[0];
    float4 pb = ((const float4*)pr)[1];
    float4 ta = ((const float4*)tr)[0];
    float4 tb = ((const float4*)tr)[1];
    float p[CC] = {pa.x,pa.y,pa.z,pa.w,pb.x,pb.y,pb.z,pb.w};
    float t[CC] = {ta.x,ta.y,ta.z,ta.w,tb.x,tb.y,tb.z,tb.w};

    float x2 = 0.f, y2 = 0.f, msep = 0.f;
    #pragma unroll
    for (int c = 0; c < CC; ++c) {
        x2 = fmaf(p[c], p[c], x2);
        y2 = fmaf(t[c], t[c], y2);
        float d = p[c] - t[c];
        msep = fmaf(d, d, msep);
    }
    s_t4[i][0] = ta; s_t4[i][1] = tb; s_y2[i] = y2;

    // fused MSE partial
    #pragma unroll
    for (int off = 32; off > 0; off >>= 1)
        msep += __shfl_down(msep, off, 64);
    if (l == 0) s_red[w] = msep;

    __syncthreads();
    if (i == 0) {
        float sum = 0.f;
        #pragma unroll
        for (int q = 0; q < 16; ++q) sum += s_red[q];
        ws[b] = sum;
    }

    const float invg = 1.0f / GAMMA_;
    float r1 = FINF, r2 = FINF;        // r_{k-1}(i), r_{k-2}(i)
    float tf[CC];                      // flowing target column t_{k-i}
    float y2f = 0.f;
    #pragma unroll
    for (int c = 0; c < CC; ++c) tf[c] = 0.f;

    const int lastk = base + 63 + TT - 1;   // last diagonal with a valid row here

    for (int s = 0; s < NSTEP; ++s) {
        const int k0 = DB * (s - w);        // this wave's diagonal window
        int klo = (k0 < base) ? base : k0;  // never skip k>=base (t-flow!)
        int khi = k0 + DB - 1;
        if (khi > lastk) khi = lastk;
        if (khi > 2*TT - 2) khi = 2*TT - 2;
        if (klo <= khi) {
            #pragma unroll
            for (int d = 0; d < DB; ++d) {
                const int k = k0 + d;
                if (k < klo || k > khi) continue;   // wave-uniform
                float tn0,tn1,tn2,tn3,tn4,tn5,tn6,tn7, y2n, hu, hd;
                if (l == 0) {
                    const int j0 = k - base;        // >= 0 by klo
                    if (j0 < TT) {
                        float4 a = s_t4[j0][0], c4 = s_t4[j0][1];
                        tn0=a.x; tn1=a.y; tn2=a.z; tn3=a.w;
                        tn4=c4.x; tn5=c4.y; tn6=c4.z; tn7=c4.w;
                        y2n = s_y2[j0];
                    }
                    if (w == 0) { hu = FINF; hd = (k == 0) ? 0.0f : FINF; }
                    else {
                        hu = s_halo[w-1][(k-1) & 63];
                        hd = s_halo[w-1][(k-2) & 63];
                    }
                }
                tf[0] = shflup1(tn0, tf[0]);
                tf[1] = shflup1(tn1, tf[1]);
                tf[2] = shflup1(tn2, tf[2]);
                tf[3] = shflup1(tn3, tf[3]);
                tf[4] = shflup1(tn4, tf[4]);
                tf[5] = shflup1(tn5, tf[5]);
                tf[6] = shflup1(tn6, tf[6]);
                tf[7] = shflup1(tn7, tf[7]);
                y2f = shflup1(y2n, y2f);
                const float up   = shflup1(hu, r1);
                const float dg   = shflup1(hd, r2);
                const float left = r1;
                const int j = k - i;
                float rn = FINF;
                if (j >= 0 && j < TT) {
                    float dot = 0.f;
                    #pragma unroll
                    for (int c = 0; c < CC; ++c) dot = fmaf(p[c], tf[c], dot);
                    const float Dv = fmaf(-2.0f, dot, x2 + y2f);
                    const float m = fminf(fminf(up, left), dg);
                    const float e = __expf((m - up)   * invg)
                                  + __expf((m - left) * invg)
                                  + __expf((m - dg)   * invg);
                    rn = Dv + m - GAMMA_ * __logf(e);
                }
                r2 = r1; r1 = rn;
                if (l == 63) s_halo[w][k & 63] = rn;
            }
        }
        __syncthreads();
    }
    if (i == TT - 1) ws[BB + b] = r1;   // r_{2046}(1023)
}

__global__ __launch_bounds__(64) void finalize_kernel(
    const float* __restrict__ ws, float* __restrict__ out)
{
    int t = threadIdx.x;
    float mse = ws[t];
    float sd  = ws[BB + t];
    #pragma unroll
    for (int off = 32; off > 0; off >>= 1) {
        mse += __shfl_down(mse, off, 64);
        sd  += __shfl_down(sd,  off, 64);
    }
    if (t == 0) {
        float msev = mse / (float)((size_t)BB * TT * CC);
        float sdtw = sd  / (float)BB;
        out[0] = ALPHA_ * msev + (1.0f - ALPHA_) * sdtw;
    }
}

extern "C" void kernel_launch(void* const* d_in, const int* in_sizes, int n_in,
                              void* d_out, int out_size, void* d_ws, size_t ws_size,
                              hipStream_t stream) {
    const float* pred   = (const float*)d_in[0];
    const float* target = (const float*)d_in[1];
    float* ws  = (float*)d_ws;
    float* out = (float*)d_out;

    sdtw_kernel<<<BB, TT, 0, stream>>>(pred, target, ws);
    finalize_kernel<<<1, 64, 0, stream>>>(ws, out);
}

// Round 4
// 512.631 us; speedup vs baseline: 1.9049x; 1.9049x over previous
//
#include <hip/hip_runtime.h>

// CombinedLoss: 0.7*MSE + 0.3*mean_b softDTW_gamma.  B=64, T=1024, C=8, fp32.
// One block (16 waves) per batch. Rhombus-skewed anti-diagonal DP:
//  - wave w owns rows [64w,64w+63]; r_{k-1}, r_{k-2} in VGPRs
//  - neighbor row via DPP wave_shr:1; wave-boundary halo via 64-deep LDS ring
//  - wave w processes only diagonals [64w, 64w+1086] (skips invalid work)
//  - all window bounds are readfirstlane-scalar -> s_cbranch skips, no
//    predicated dead bodies (R2's 2x issue waste)
//  - target columns read directly from LDS channel-major (-2*t prescaled),
//    one med3-clamped address + immediate offsets, <=2-way bank alias (free)
//  - barrier every DB=16 diagonals (143 total)

constexpr int BB = 64;
constexpr int TT = 1024;
constexpr int CC = 8;
constexpr float ALPHA_ = 0.7f;
constexpr float GAMMA_ = 0.2f;
constexpr float FINF = 1000000000.0f;
constexpr int DB = 16;
constexpr int NSTEP = 143;   // ceil(2047/16) + 15 skew steps

// lane l <- v from lane l-1; lane 0 <- old0[lane0]  (v_mov_b32 dpp wave_shr:1)
__device__ __forceinline__ float shflup1(float old0, float v) {
    return __int_as_float(__builtin_amdgcn_update_dpp(
        __float_as_int(old0), __float_as_int(v),
        0x138 /* wave_shr:1 */, 0xf, 0xf, false));
}

__global__ __launch_bounds__(1024) void sdtw_kernel(
    const float* __restrict__ pred, const float* __restrict__ target,
    float* __restrict__ ws)
{
    __shared__ float s_tc[9][TT];      // [c][j] = -2*t_c(j); [8][j] = y2(j)
    __shared__ float s_halo[16][64];   // per-wave top-row ring
    __shared__ float s_red[16];

    const int b = blockIdx.x;
    const int i = threadIdx.x;                       // row
    const int l = i & 63;
    const int wid  = __builtin_amdgcn_readfirstlane(i >> 6);  // scalar wave id
    const int base = wid << 6;

    const float* pr = pred   + ((size_t)b * TT + i) * CC;
    const float* tr = target + ((size_t)b * TT + i) * CC;
    float4 pa = ((const float4*)pr)[0];
    float4 pb = ((const float4*)pr)[1];
    float4 ta = ((const float4*)tr)[0];
    float4 tb = ((const float4*)tr)[1];
    float p[CC] = {pa.x,pa.y,pa.z,pa.w,pb.x,pb.y,pb.z,pb.w};
    float t[CC] = {ta.x,ta.y,ta.z,ta.w,tb.x,tb.y,tb.z,tb.w};

    float x2 = 0.f, y2 = 0.f, msep = 0.f;
    #pragma unroll
    for (int c = 0; c < CC; ++c) {
        x2 = fmaf(p[c], p[c], x2);
        y2 = fmaf(t[c], t[c], y2);
        float d = p[c] - t[c];
        msep = fmaf(d, d, msep);
        s_tc[c][i] = -2.0f * t[c];
    }
    s_tc[8][i] = y2;

    // fused MSE partial
    #pragma unroll
    for (int off = 32; off > 0; off >>= 1)
        msep += __shfl_down(msep, off, 64);
    if (l == 0) s_red[wid] = msep;
    __syncthreads();
    if (i == 0) {
        float s = 0.f;
        #pragma unroll
        for (int q = 0; q < 16; ++q) s += s_red[q];
        ws[b] = s;
    }

    const float c1 = 7.21347520f;   // (1/gamma)*log2(e)
    const float c2 = 0.13862944f;   // gamma*ln(2)
    float r1 = FINF, r2 = FINF;     // r_{k-1}(i), r_{k-2}(i)
    const int lastk = base + 63 + TT - 1;

    auto diag = [&](int k) {        // k is wave-uniform (SGPR)
        float hu, hd;
        if (wid == 0) { hu = FINF; hd = (k == 0) ? 0.0f : FINF; }
        else {                       // same-address broadcast reads (free)
            hu = s_halo[wid - 1][(k - 1) & 63];
            hd = s_halo[wid - 1][(k - 2) & 63];
        }
        const float up   = shflup1(hu, r1);
        const float dg   = shflup1(hd, r2);
        const float left = r1;
        const int j  = k - i;
        const int jc = min(max(j, 0), TT - 1);       // v_med3
        float acc = x2 + s_tc[8][jc];                 // x2 + y2(j)
        #pragma unroll
        for (int c = 0; c < CC; ++c)
            acc = fmaf(p[c], s_tc[c][jc], acc);       // += p . (-2 t)
        const float m = fminf(fminf(up, left), dg);
        const float e = __builtin_amdgcn_exp2f((m - up)   * c1)
                      + __builtin_amdgcn_exp2f((m - left) * c1)
                      + __builtin_amdgcn_exp2f((m - dg)   * c1);
        float rn = acc + m - c2 * __builtin_amdgcn_logf(e);
        rn = ((unsigned)j < (unsigned)TT) ? rn : FINF;
        r2 = r1; r1 = rn;
        if (l == 63) s_halo[wid][k & 63] = rn;
    };

    for (int s = 0; s < NSTEP; ++s) {
        const int k0 = DB * (s - wid);               // SGPR window
        int klo = (k0 < base) ? base : k0;
        int khi = k0 + DB - 1;
        if (khi > lastk) khi = lastk;
        if (klo == k0 && khi == k0 + DB - 1) {       // full window: unrolled
            #pragma unroll
            for (int d = 0; d < DB; ++d) diag(k0 + d);
        } else if (klo <= khi) {                     // edge window: dynamic
            for (int k = klo; k <= khi; ++k) diag(k);
        }
        __syncthreads();
    }
    if (i == TT - 1) ws[BB + b] = r1;                // r_{2T-2}(T-1)
}

__global__ __launch_bounds__(64) void finalize_kernel(
    const float* __restrict__ ws, float* __restrict__ out)
{
    int t = threadIdx.x;
    float mse = ws[t];
    float sd  = ws[BB + t];
    #pragma unroll
    for (int off = 32; off > 0; off >>= 1) {
        mse += __shfl_down(mse, off, 64);
        sd  += __shfl_down(sd,  off, 64);
    }
    if (t == 0) {
        float msev = mse / (float)((size_t)BB * TT * CC);
        float sdtw = sd  / (float)BB;
        out[0] = ALPHA_ * msev + (1.0f - ALPHA_) * sdtw;
    }
}

extern "C" void kernel_launch(void* const* d_in, const int* in_sizes, int n_in,
                              void* d_out, int out_size, void* d_ws, size_t ws_size,
                              hipStream_t stream) {
    const float* pred   = (const float*)d_in[0];
    const float* target = (const float*)d_in[1];
    float* ws  = (float*)d_ws;
    float* out = (float*)d_out;

    sdtw_kernel<<<BB, TT, 0, stream>>>(pred, target, ws);
    finalize_kernel<<<1, 64, 0, stream>>>(ws, out);
}